// Round 2
// baseline (134536.975 us; speedup 1.0000x reference)
//
#include <hip/hip_runtime.h>

#define T_STEPS 65536
#define IN_DIM 5
#define H1 26
#define H2 121

__device__ __forceinline__ float fsig(float x) {
    float e = __builtin_amdgcn_exp2f(-1.44269504f * x);
    return __builtin_amdgcn_rcpf(1.0f + e);
}
__device__ __forceinline__ float ftanh(float x) {
    float e = __builtin_amdgcn_exp2f(2.88539008f * x);
    return 1.0f - 2.0f * __builtin_amdgcn_rcpf(e + 1.0f);
}

#define FOR16(F) F(0) F(1) F(2) F(3) F(4) F(5) F(6) F(7) F(8) F(9) F(10) F(11) F(12) F(13) F(14) F(15)
#define FOR64(F) F(0) F(1) F(2) F(3) F(4) F(5) F(6) F(7) F(8) F(9) F(10) F(11) F(12) F(13) F(14) F(15) \
                 F(16) F(17) F(18) F(19) F(20) F(21) F(22) F(23) F(24) F(25) F(26) F(27) F(28) F(29) F(30) F(31) \
                 F(32) F(33) F(34) F(35) F(36) F(37) F(38) F(39) F(40) F(41) F(42) F(43) F(44) F(45) F(46) F(47) \
                 F(48) F(49) F(50) F(51) F(52) F(53) F(54) F(55) F(56) F(57) F(58) F(59) F(60) F(61) F(62) F(63)

// One persistent workgroup. 1024 threads = 16 waves (4/SIMD).
// threads 0..959       : gates2 rows 0..479, 2 threads/row (half=tid&1)
// wave 15 lanes 0..51  : LSTM1 (rows l, l+52), act by lanes<26 (intra-wave only)
// wave 15 lanes 52..59 : gates2 rows 480..483 (2 threads/row)
// wave 15 lane 60      : y-store of previous step
// threads 0..127       : h2/c2 activation + y butterfly reduce (after B2)
//
// Weight registers (named scalars, union across roles):
//  gates2:  w0..w63 = W_hh2 half-row (zero pad past 121), u0..u15 = W_ih2 half-row
//  LSTM1:   w0..w25 = W_hh1 row r, w32..w57 = W_hh1 row r+52 (w26..31,w58..63 = 0)
//           u0..u4 = W_ih1 row r, u5..u9 = W_ih1 row r+52, u10/u11 = biases, u12 = c1
__global__ __launch_bounds__(1024, 1) void lstm_seq_kernel(
    const float* __restrict__ x,
    const float* __restrict__ W_ih1, const float* __restrict__ W_hh1,
    const float* __restrict__ b_ih1, const float* __restrict__ b_hh1,
    const float* __restrict__ W_ih2, const float* __restrict__ W_hh2,
    const float* __restrict__ b_ih2, const float* __restrict__ b_hh2,
    const float* __restrict__ W_lin, const float* __restrict__ b_lin,
    const float* __restrict__ h1_0, const float* __restrict__ c1_0,
    const float* __restrict__ h2_0, const float* __restrict__ c2_0,
    float* __restrict__ out)
{
    __shared__ __align__(16) float h1_lds[32];    // 26 + zero pad
    __shared__ __align__(16) float h2_lds[128];   // 121 + zero pad
    __shared__ float g1_lds[104];
    __shared__ float g2_lds[484];
    __shared__ float ypart[2];

    const int tid = threadIdx.x;
    const int lane15 = tid - 960;                 // valid when tid>=960
    const bool in_w15 = (tid >= 960);
    const bool is_g2 = (tid < 960) || (lane15 >= 52 && lane15 < 60);
    const int row  = (tid < 960) ? (tid >> 1) : (480 + ((tid - 1012) >> 1));
    const int half = tid & 1;

    // ---- one-time init through scratch temps (outside the hot loop) ----
    float wt[64], ut[16];
    for (int i = 0; i < 64; ++i) wt[i] = 0.0f;
    for (int i = 0; i < 16; ++i) ut[i] = 0.0f;

    float c2 = 0.0f, wlin = 0.0f, accbias = 0.0f;

    if (is_g2) {
        const float* wp = W_hh2 + row * H2;
        for (int m = 0; m < 64; ++m) {
            int k = half * 64 + m;
            wt[m] = (k < H2) ? wp[k] : 0.0f;
        }
        const float* up = W_ih2 + row * H1;
        for (int m = 0; m < 16; ++m) {
            int k = half * 16 + m;
            ut[m] = (k < H1) ? up[k] : 0.0f;
        }
        accbias = (half == 0) ? (b_ih2[row] + b_hh2[row]) : 0.0f;
    } else if (in_w15 && lane15 < 52) {
        const int r0 = lane15, r1 = lane15 + 52;
        for (int k = 0; k < H1; ++k) {
            wt[k]      = W_hh1[r0 * H1 + k];
            wt[32 + k] = W_hh1[r1 * H1 + k];
        }
        for (int i = 0; i < 5; ++i) {
            ut[i]     = W_ih1[r0 * 5 + i];
            ut[5 + i] = W_ih1[r1 * 5 + i];
        }
        ut[10] = b_ih1[r0] + b_hh1[r0];
        ut[11] = b_ih1[r1] + b_hh1[r1];
        if (lane15 < H1) ut[12] = c1_0[lane15];
    }
    if (tid < H2) { c2 = c2_0[tid]; wlin = W_lin[tid]; }

    // ---- promote to named scalar registers (loop body touches ONLY these) ----
#define DECW(i) float w##i = wt[i];
    FOR64(DECW)
#define DECU(i) float u##i = ut[i];
    FOR16(DECU)

    if (tid < 32)  h1_lds[tid] = (tid < H1) ? h1_0[tid] : 0.0f;
    if (tid < 128) h2_lds[tid] = (tid < H2) ? h2_0[tid] : 0.0f;
    const float blin = b_lin[0];
    __syncthreads();

    const float4* h2v4 = reinterpret_cast<const float4*>(h2_lds);
    const float4* h1v4 = reinterpret_cast<const float4*>(h1_lds);

    float acc = 0.0f;

    for (int t = 0; t < T_STEPS; ++t) {
        // ---------------- Phase A: W_hh2 @ h2(t-1), LSTM1, y-store ----------
        if (is_g2) {
            acc = accbias;
#define PHA(q,a,b,c,d) { float4 h = h2v4[half * 16 + q]; \
            acc = fmaf(w##a, h.x, acc); acc = fmaf(w##b, h.y, acc); \
            acc = fmaf(w##c, h.z, acc); acc = fmaf(w##d, h.w, acc); }
            PHA(0,0,1,2,3)     PHA(1,4,5,6,7)     PHA(2,8,9,10,11)    PHA(3,12,13,14,15)
            PHA(4,16,17,18,19) PHA(5,20,21,22,23) PHA(6,24,25,26,27)  PHA(7,28,29,30,31)
            PHA(8,32,33,34,35) PHA(9,36,37,38,39) PHA(10,40,41,42,43) PHA(11,44,45,46,47)
            PHA(12,48,49,50,51) PHA(13,52,53,54,55) PHA(14,56,57,58,59) PHA(15,60,61,62,63)
        }
        if (in_w15) {
            if (lane15 < 52) {
                const float* xt = x + t * IN_DIM;
                float x0 = xt[0], x1 = xt[1], x2 = xt[2], x3 = xt[3], x4 = xt[4];
                float g0 = u10, g1v = u11;
                g0  = fmaf(u0, x0, g0);  g0  = fmaf(u1, x1, g0);  g0  = fmaf(u2, x2, g0);
                g0  = fmaf(u3, x3, g0);  g0  = fmaf(u4, x4, g0);
                g1v = fmaf(u5, x0, g1v); g1v = fmaf(u6, x1, g1v); g1v = fmaf(u7, x2, g1v);
                g1v = fmaf(u8, x3, g1v); g1v = fmaf(u9, x4, g1v);
#define PH1(q,a0,a1,a2,a3,b0,b1,b2,b3) { float4 h = h1v4[q]; \
                g0  = fmaf(w##a0, h.x, g0);  g0  = fmaf(w##a1, h.y, g0); \
                g0  = fmaf(w##a2, h.z, g0);  g0  = fmaf(w##a3, h.w, g0); \
                g1v = fmaf(w##b0, h.x, g1v); g1v = fmaf(w##b1, h.y, g1v); \
                g1v = fmaf(w##b2, h.z, g1v); g1v = fmaf(w##b3, h.w, g1v); }
                PH1(0, 0,1,2,3,     32,33,34,35)
                PH1(1, 4,5,6,7,     36,37,38,39)
                PH1(2, 8,9,10,11,   40,41,42,43)
                PH1(3, 12,13,14,15, 44,45,46,47)
                PH1(4, 16,17,18,19, 48,49,50,51)
                PH1(5, 20,21,22,23, 52,53,54,55)
                PH1(6, 24,25,26,27, 56,57,58,59)
                PH1(7, 28,29,30,31, 60,61,62,63)
                g1_lds[lane15]      = g0;
                g1_lds[lane15 + 52] = g1v;
                asm volatile("s_waitcnt lgkmcnt(0)" ::: "memory");
                if (lane15 < H1) {
                    float gi = g1_lds[lane15];
                    float gf = g1_lds[H1 + lane15];
                    float gg = g1_lds[2 * H1 + lane15];
                    float go = g1_lds[3 * H1 + lane15];
                    float c1 = u12;
                    c1 = fsig(gf) * c1 + fsig(gi) * ftanh(gg);
                    u12 = c1;
                    h1_lds[lane15] = fsig(go) * ftanh(c1);
                }
            } else if (lane15 == 60) {
                if (t > 0) out[t - 1] = ypart[0] + ypart[1] + blin;
            }
        }
        __syncthreads();  // B1: h1(t) visible

        // ---------------- Phase C: += W_ih2 @ h1(t), combine halves ---------
        if (is_g2) {
#define PHC(q,a,b,c,d) { float4 h = h1v4[half * 4 + q]; \
            acc = fmaf(u##a, h.x, acc); acc = fmaf(u##b, h.y, acc); \
            acc = fmaf(u##c, h.z, acc); acc = fmaf(u##d, h.w, acc); }
            PHC(0,0,1,2,3) PHC(1,4,5,6,7) PHC(2,8,9,10,11) PHC(3,12,13,14,15)
            acc += __shfl_xor(acc, 1);
            if (half == 0) g2_lds[row] = acc;
        }
        __syncthreads();  // B2: gates2 visible

        // ---------------- Act: c2/h2 update + y partial reduce --------------
        if (tid < 128) {
            float p = 0.0f;
            if (tid < H2) {
                float gi = g2_lds[tid];
                float gf = g2_lds[H2 + tid];
                float gg = g2_lds[2 * H2 + tid];
                float go = g2_lds[3 * H2 + tid];
                c2 = fsig(gf) * c2 + fsig(gi) * ftanh(gg);
                float h2n = fsig(go) * ftanh(c2);
                h2_lds[tid] = h2n;
                p = h2n * wlin;
            }
            #pragma unroll
            for (int off = 32; off >= 1; off >>= 1)
                p += __shfl_xor(p, off);
            if ((tid & 63) == 0) ypart[tid >> 6] = p;
        }
        __syncthreads();  // B3: h2(t), ypart visible
    }

    if (tid == 1020) out[T_STEPS - 1] = ypart[0] + ypart[1] + blin;
}

extern "C" void kernel_launch(void* const* d_in, const int* in_sizes, int n_in,
                              void* d_out, int out_size, void* d_ws, size_t ws_size,
                              hipStream_t stream) {
    const float* x     = (const float*)d_in[0];
    const float* W_ih1 = (const float*)d_in[1];
    const float* W_hh1 = (const float*)d_in[2];
    const float* b_ih1 = (const float*)d_in[3];
    const float* b_hh1 = (const float*)d_in[4];
    const float* W_ih2 = (const float*)d_in[5];
    const float* W_hh2 = (const float*)d_in[6];
    const float* b_ih2 = (const float*)d_in[7];
    const float* b_hh2 = (const float*)d_in[8];
    const float* W_lin = (const float*)d_in[9];
    const float* b_lin = (const float*)d_in[10];
    const float* h1_0  = (const float*)d_in[11];
    const float* c1_0  = (const float*)d_in[12];
    const float* h2_0  = (const float*)d_in[13];
    const float* c2_0  = (const float*)d_in[14];
    float* out = (float*)d_out;

    hipLaunchKernelGGL(lstm_seq_kernel, dim3(1), dim3(1024), 0, stream,
                       x, W_ih1, W_hh1, b_ih1, b_hh1,
                       W_ih2, W_hh2, b_ih2, b_hh2,
                       W_lin, b_lin, h1_0, c1_0, h2_0, c2_0, out);
}